// Round 1
// baseline (6228.016 us; speedup 1.0000x reference)
//
#include <hip/hip_runtime.h>
#include <hip/hip_bf16.h>

typedef __hip_bfloat16 bf16;

#define B_   16
#define CIN  256
#define CQK  32
#define CV   128
#define VDIM 64
#define TDIM 64
#define P    (VDIM * TDIM)   // 4096

// ---------------------------------------------------------------------------
// Kernel 1: fused q/k/v 3x3 conv (stride1, SAME).
//   x: [B, CIN, V, T] fp32
//   q,k out: [B, T, V, CQK] fp32 (transposed layout for attention)
//   v  out:  [B, T, V, CV ] bf16
// grid = B * NCG * (P/256), NCG = 24 channel-groups of 8 (4 q, 4 k, 16 v)
// Each thread: 1 pixel, 8 output channels.
// ---------------------------------------------------------------------------
__global__ __launch_bounds__(256) void qkv_conv(
    const float* __restrict__ x,
    const float* __restrict__ wq,
    const float* __restrict__ wk,
    const float* __restrict__ wv,
    float* __restrict__ qo,
    float* __restrict__ ko,
    bf16* __restrict__ vo)
{
    const int bid   = blockIdx.x;
    const int ptile = bid & 15;          // P/256 = 16 tiles
    const int cg    = (bid >> 4) % 24;
    const int b     = bid / (16 * 24);
    const int tid   = threadIdx.x;
    const int p     = ptile * 256 + tid;
    const int y     = p >> 6;            // V (height) index
    const int t     = p & 63;            // T (width) index

    const float* w;
    int oc0, mode;
    if (cg < 4)       { w = wq; oc0 = cg * 8;        mode = 0; }
    else if (cg < 8)  { w = wk; oc0 = (cg - 4) * 8;  mode = 1; }
    else              { w = wv; oc0 = (cg - 8) * 8;  mode = 2; }

    float acc[8];
#pragma unroll
    for (int j = 0; j < 8; ++j) acc[j] = 0.f;

    const float* xb = x + (size_t)b * CIN * P;

    for (int ci = 0; ci < CIN; ++ci) {
        const float* xp = xb + (size_t)ci * P;
        const float* wc = w + (size_t)oc0 * CIN * 9 + ci * 9;
#pragma unroll
        for (int dy = 0; dy < 3; ++dy) {
            const int yy = y + dy - 1;
            const bool vy = (yy >= 0) & (yy < VDIM);
            const int ycl = min(max(yy, 0), VDIM - 1);
#pragma unroll
            for (int dx = 0; dx < 3; ++dx) {
                const int xx = t + dx - 1;
                const bool ok = vy & (xx >= 0) & (xx < TDIM);
                const int xcl = min(max(xx, 0), TDIM - 1);
                float xv = xp[ycl * TDIM + xcl];
                xv = ok ? xv : 0.f;
#pragma unroll
                for (int j = 0; j < 8; ++j)
                    acc[j] += wc[(size_t)j * CIN * 9 + dy * 3 + dx] * xv;
            }
        }
    }

    const size_t obase = ((size_t)b * TDIM + t) * VDIM + y;
    if (mode == 0) {
#pragma unroll
        for (int j = 0; j < 8; ++j) qo[obase * CQK + oc0 + j] = acc[j];
    } else if (mode == 1) {
#pragma unroll
        for (int j = 0; j < 8; ++j) ko[obase * CQK + oc0 + j] = acc[j];
    } else {
#pragma unroll
        for (int j = 0; j < 8; ++j) vo[obase * CV + oc0 + j] = __float2bfloat16(acc[j]);
    }
}

// ---------------------------------------------------------------------------
// Kernel 2: attention per (b,t). grid = B*T = 1024, 256 threads.
//   q,k: [B,T,V,32] fp32 ; v: [B,T,V,128] bf16
//   attn_out: [B*T, 64, 64] fp32 ; av out: [B,T,V,128] bf16
// ---------------------------------------------------------------------------
__global__ __launch_bounds__(256) void attention(
    const float* __restrict__ q,
    const float* __restrict__ k,
    const bf16* __restrict__ v,
    float* __restrict__ attn_out,
    bf16* __restrict__ av)
{
    const int bt  = blockIdx.x;
    const int tid = threadIdx.x;

    __shared__ float qs[64][33];
    __shared__ float ks[64][33];
    __shared__ float S[64][65];
    __shared__ float vs[64][128];

    const float* qb = q + (size_t)bt * 64 * 32;
    const float* kb = k + (size_t)bt * 64 * 32;
    for (int i = tid; i < 64 * 32; i += 256) {
        qs[i >> 5][i & 31] = qb[i];
        ks[i >> 5][i & 31] = kb[i];
    }
    const bf16* vb = v + (size_t)bt * 64 * 128;
    for (int i = tid; i < 64 * 128; i += 256)
        vs[i >> 7][i & 127] = __bfloat162float(vb[i]);
    __syncthreads();

    // S = q k^T  (64x64, K=32)
    for (int idx = tid; idx < 4096; idx += 256) {
        const int i = idx >> 6, j = idx & 63;
        float s = 0.f;
#pragma unroll
        for (int c = 0; c < 32; ++c) s += qs[i][c] * ks[j][c];
        S[i][j] = s;
    }
    __syncthreads();

    // softmax over rows: 4 lanes per row, 16 cols each
    {
        const int row = tid >> 2, sub = tid & 3;
        float m = -INFINITY;
#pragma unroll
        for (int jj = 0; jj < 16; ++jj) m = fmaxf(m, S[row][sub * 16 + jj]);
        m = fmaxf(m, __shfl_xor(m, 1));
        m = fmaxf(m, __shfl_xor(m, 2));
        float e[16], sum = 0.f;
#pragma unroll
        for (int jj = 0; jj < 16; ++jj) {
            e[jj] = expf(S[row][sub * 16 + jj] - m);
            sum += e[jj];
        }
        sum += __shfl_xor(sum, 1);
        sum += __shfl_xor(sum, 2);
        const float inv = 1.f / sum;
#pragma unroll
        for (int jj = 0; jj < 16; ++jj) S[row][sub * 16 + jj] = e[jj] * inv;
    }
    __syncthreads();

    // write attn (coalesced)
    float* ao = attn_out + (size_t)bt * 4096;
    for (int idx = tid; idx < 4096; idx += 256)
        ao[idx] = S[idx >> 6][idx & 63];

    // AV: av[i][c] = sum_j S[i][j] * v[j][c]; thread = (i = tid&63, quad = tid>>6)
    {
        const int i = tid & 63, quad = tid >> 6;
        float acc[32];
#pragma unroll
        for (int cc = 0; cc < 32; ++cc) acc[cc] = 0.f;
        for (int j = 0; j < 64; ++j) {
            const float s = S[i][j];
#pragma unroll
            for (int cc = 0; cc < 32; ++cc)
                acc[cc] += s * vs[j][quad * 32 + cc];
        }
        bf16* avb = av + (size_t)bt * 64 * 128 + (size_t)i * 128 + quad * 32;
#pragma unroll
        for (int cc = 0; cc < 32; ++cc) avb[cc] = __float2bfloat16(acc[cc]);
    }
}

// ---------------------------------------------------------------------------
// Kernel 3: out = x + sigma * conv3x3(av, wo)
//   av: [B,T,V,128] bf16 (transposed conv input), wo: [256,128,3,3] fp32
//   out: [B,256,V,T] fp32
// grid = B * 32 * 16, each thread 8 channels x 1 pixel
// ---------------------------------------------------------------------------
__global__ __launch_bounds__(256) void out_conv(
    const float* __restrict__ x,
    const float* __restrict__ wo,
    const bf16* __restrict__ av,
    const float* __restrict__ sigma,
    float* __restrict__ out)
{
    const int bid   = blockIdx.x;
    const int ptile = bid & 15;
    const int cg    = (bid >> 4) & 31;
    const int b     = bid >> 9;
    const int tid   = threadIdx.x;
    const int p     = ptile * 256 + tid;
    const int y     = p >> 6;            // V index
    const int t     = p & 63;            // T index
    const int oc0   = cg * 8;

    float acc[8];
#pragma unroll
    for (int j = 0; j < 8; ++j) acc[j] = 0.f;

    const bf16* ab = av + (size_t)b * P * CV;

    for (int ci = 0; ci < CV; ++ci) {
        const float* wc = wo + (size_t)oc0 * CV * 9 + ci * 9;
#pragma unroll
        for (int dy = 0; dy < 3; ++dy) {
            const int yy = y + dy - 1;
            const bool vy = (yy >= 0) & (yy < VDIM);
            const int ycl = min(max(yy, 0), VDIM - 1);
#pragma unroll
            for (int dx = 0; dx < 3; ++dx) {
                const int xx = t + dx - 1;
                const bool ok = vy & (xx >= 0) & (xx < TDIM);
                const int xcl = min(max(xx, 0), TDIM - 1);
                float a = __bfloat162float(ab[((size_t)xcl * VDIM + ycl) * CV + ci]);
                a = ok ? a : 0.f;
#pragma unroll
                for (int j = 0; j < 8; ++j)
                    acc[j] += wc[(size_t)j * CV * 9 + dy * 3 + dx] * a;
            }
        }
    }

    const float s = sigma[0];
    const size_t xb = (((size_t)b * CIN + oc0) * VDIM + y) * TDIM + t;
#pragma unroll
    for (int j = 0; j < 8; ++j)
        out[xb + (size_t)j * P] = x[xb + (size_t)j * P] + s * acc[j];
}

// ---------------------------------------------------------------------------
extern "C" void kernel_launch(void* const* d_in, const int* in_sizes, int n_in,
                              void* d_out, int out_size, void* d_ws, size_t ws_size,
                              hipStream_t stream)
{
    const float* x     = (const float*)d_in[0];
    const float* wq    = (const float*)d_in[1];
    const float* wk    = (const float*)d_in[2];
    const float* wv    = (const float*)d_in[3];
    const float* wo    = (const float*)d_in[4];
    const float* sigma = (const float*)d_in[5];

    float* out      = (float*)d_out;                       // [16,256,64,64]
    float* attn_out = out + (size_t)B_ * CIN * P;          // [1024,64,64]

    // ws layout: q fp32 (8MB) | k fp32 (8MB) | v bf16 (16MB) | av bf16 (16MB)
    float* q  = (float*)d_ws;
    float* k  = q + (size_t)B_ * TDIM * VDIM * CQK;        // 2,097,152 floats
    bf16*  v  = (bf16*)(k + (size_t)B_ * TDIM * VDIM * CQK);
    bf16*  av = v + (size_t)B_ * TDIM * VDIM * CV;         // 8,388,608 bf16

    qkv_conv<<<B_ * 24 * (P / 256), 256, 0, stream>>>(x, wq, wk, wv, q, k, v);
    attention<<<B_ * TDIM, 256, 0, stream>>>(q, k, v, attn_out, av);
    out_conv<<<B_ * 32 * (P / 256), 256, 0, stream>>>(x, wo, av, sigma, out);
}

// Round 2
// 666.080 us; speedup vs baseline: 9.3503x; 9.3503x over previous
//
#include <hip/hip_runtime.h>
#include <hip/hip_bf16.h>

typedef __hip_bfloat16 bf16;
typedef float f32x4 __attribute__((ext_vector_type(4)));
typedef short s16x8 __attribute__((ext_vector_type(8)));

#define B_   16
#define CIN  256
#define CQK  32
#define CV   128
#define VDIM 64
#define TDIM 64
#define P    (VDIM * TDIM)   // 4096

static __device__ __forceinline__ ushort f2bf(float f) {
    bf16 h = __float2bfloat16(f);
    return *(ushort*)&h;
}

// ---------------------------------------------------------------------------
// repack_w: wv [128][256][3][3] -> wvT [9][128][256] bf16
//           wo [256][128][3][3] -> woT [9][256][128] bf16
// ---------------------------------------------------------------------------
__global__ __launch_bounds__(256) void repack_w(
    const float* __restrict__ wv, const float* __restrict__ wo,
    ushort* __restrict__ wvT, ushort* __restrict__ woT)
{
    int i = blockIdx.x * 256 + threadIdx.x;
    if (i < 9 * 128 * 256) {
        int tap = i / (128 * 256);
        int r   = i % (128 * 256);
        int oc  = r >> 8;
        int ci  = r & 255;
        wvT[i] = f2bf(wv[(size_t)oc * 2304 + ci * 9 + tap]);
    } else {
        i -= 9 * 128 * 256;
        int tap = i / (256 * 128);
        int r   = i % (256 * 128);
        int oc  = r >> 7;
        int ci  = r & 127;
        woT[i] = f2bf(wo[(size_t)oc * 1152 + ci * 9 + tap]);
    }
}

// ---------------------------------------------------------------------------
// repack_x: x [B][256][64y][64t] fp32 -> xT [B][64t][64y][256ci] bf16
// block = (b, y). LDS transpose.
// ---------------------------------------------------------------------------
__global__ __launch_bounds__(256) void repack_x(
    const float* __restrict__ x, ushort* __restrict__ xT)
{
    const int b = blockIdx.x >> 6;
    const int y = blockIdx.x & 63;
    __shared__ ushort tile[64][257];
    const int t  = threadIdx.x & 63;
    const int cq = threadIdx.x >> 6;
    const float* xb = x + (((size_t)b * CIN) * VDIM + y) * TDIM;
    for (int ci = cq; ci < 256; ci += 4)
        tile[t][ci] = f2bf(xb[(size_t)ci * P + t]);
    __syncthreads();
    const int ci4 = (threadIdx.x & 63) * 4;
    const int tr0 = threadIdx.x >> 6;
    for (int tr = tr0; tr < 64; tr += 4) {
        ushort4 u;
        u.x = tile[tr][ci4]; u.y = tile[tr][ci4 + 1];
        u.z = tile[tr][ci4 + 2]; u.w = tile[tr][ci4 + 3];
        *(ushort4*)(xT + ((((size_t)b * 64 + tr) * 64 + y) * 256 + ci4)) = u;
    }
}

// ---------------------------------------------------------------------------
// qk_conv: fp32 VALU conv (accuracy-critical path feeding softmax).
// grid = B * 8cg * 16ptiles; cg<4 -> q, else k. out [b][t][y][32] fp32.
// ---------------------------------------------------------------------------
__global__ __launch_bounds__(256) void qk_conv(
    const float* __restrict__ x,
    const float* __restrict__ wq,
    const float* __restrict__ wk,
    float* __restrict__ qo,
    float* __restrict__ ko)
{
    const int bid   = blockIdx.x;
    const int ptile = bid & 15;
    const int cg    = (bid >> 4) & 7;
    const int b     = bid >> 7;
    const int tid   = threadIdx.x;
    const int p     = ptile * 256 + tid;
    const int y     = p >> 6;
    const int t     = p & 63;

    const float* w = (cg < 4) ? wq : wk;
    const int oc0  = (cg & 3) * 8;

    float acc[8];
#pragma unroll
    for (int j = 0; j < 8; ++j) acc[j] = 0.f;

    const float* xb = x + (size_t)b * CIN * P;
    for (int ci = 0; ci < CIN; ++ci) {
        const float* xp = xb + (size_t)ci * P;
        const float* wc = w + (size_t)oc0 * CIN * 9 + ci * 9;
#pragma unroll
        for (int dy = 0; dy < 3; ++dy) {
            const int yy = y + dy - 1;
            const bool vy = (yy >= 0) & (yy < VDIM);
            const int ycl = min(max(yy, 0), VDIM - 1);
#pragma unroll
            for (int dx = 0; dx < 3; ++dx) {
                const int xx = t + dx - 1;
                const bool ok = vy & (xx >= 0) & (xx < TDIM);
                const int xcl = min(max(xx, 0), TDIM - 1);
                float xv = xp[ycl * TDIM + xcl];
                xv = ok ? xv : 0.f;
#pragma unroll
                for (int j = 0; j < 8; ++j)
                    acc[j] += wc[(size_t)j * CIN * 9 + dy * 3 + dx] * xv;
            }
        }
    }
    const size_t obase = (((size_t)b * TDIM + t) * VDIM + y) * CQK + oc0;
    float* o = (cg < 4) ? qo : ko;
#pragma unroll
    for (int j = 0; j < 8; ++j) o[obase + j] = acc[j];
}

// ---------------------------------------------------------------------------
// v_conv: MFMA implicit GEMM. block=(b,t0): M=128 voc, N=64 y, K=256ci*9tap.
// B-tile LDS [3 dx][66 yl][128 ci] bf16, XOR-swizzled, 2 ci-chunks.
// v out [b][t][y][128] bf16.
// ---------------------------------------------------------------------------
__global__ __launch_bounds__(256) void v_conv(
    const ushort* __restrict__ xT,
    const ushort* __restrict__ wvT,
    ushort* __restrict__ v)
{
    const int b    = blockIdx.x >> 6;
    const int t0   = blockIdx.x & 63;
    const int tid  = threadIdx.x;
    const int lane = tid & 63;
    const int w    = tid >> 6;

    __shared__ ushort btile[3 * 66 * 128];

    f32x4 acc[2][4];
#pragma unroll
    for (int m = 0; m < 2; ++m)
#pragma unroll
        for (int nf = 0; nf < 4; ++nf) acc[m][nf] = (f32x4){0.f, 0.f, 0.f, 0.f};

    for (int chunk = 0; chunk < 2; ++chunk) {
        const int ci0 = chunk * 128;
        __syncthreads();
        for (int idx = tid; idx < 198 * 16; idx += 256) {
            const int row = idx >> 4, ch = idx & 15;
            const int dx = row / 66, yl = row % 66;
            const int tp = t0 + dx - 1, yp = yl - 1;
            int4 val = {0, 0, 0, 0};
            if ((unsigned)tp < 64u && (unsigned)yp < 64u)
                val = *(const int4*)(xT + ((((size_t)b * 64 + tp) * 64 + yp) * 256 + ci0 + ch * 8));
            const int byte_off = row * 256 + ((ch * 16) ^ ((row & 7) << 4));
            *(int4*)((char*)btile + byte_off) = val;
        }
        __syncthreads();

#pragma unroll
        for (int tap = 0; tap < 9; ++tap) {
            const int dy = tap / 3, dx = tap % 3;
#pragma unroll
            for (int kk = 0; kk < 4; ++kk) {
                s16x8 bf[4];
#pragma unroll
                for (int nf = 0; nf < 4; ++nf) {
                    const int yl = nf * 16 + (lane & 15) + dy;
                    const int row = dx * 66 + yl;
                    const int bir = kk * 64 + (lane >> 4) * 16;
                    bf[nf] = *(const s16x8*)((const char*)btile + row * 256 + (bir ^ ((row & 7) << 4)));
                }
#pragma unroll
                for (int m = 0; m < 2; ++m) {
                    const int oc = w * 32 + m * 16 + (lane & 15);
                    s16x8 af = *(const s16x8*)(wvT + (size_t)(tap * 128 + oc) * 256 + ci0 + kk * 32 + (lane >> 4) * 8);
#pragma unroll
                    for (int nf = 0; nf < 4; ++nf)
                        acc[m][nf] = __builtin_amdgcn_mfma_f32_16x16x32_bf16(af, bf[nf], acc[m][nf], 0, 0, 0);
                }
            }
        }
    }

#pragma unroll
    for (int m = 0; m < 2; ++m)
#pragma unroll
        for (int nf = 0; nf < 4; ++nf) {
            const int yy = nf * 16 + (lane & 15);
            const int c0 = w * 32 + m * 16 + (lane >> 4) * 4;
            ushort4 u;
            u.x = f2bf(acc[m][nf][0]); u.y = f2bf(acc[m][nf][1]);
            u.z = f2bf(acc[m][nf][2]); u.w = f2bf(acc[m][nf][3]);
            *(ushort4*)(v + ((((size_t)b * 64 + t0) * 64 + yy) * 128 + c0)) = u;
        }
}

// ---------------------------------------------------------------------------
// attention: per (b,t). q,k fp32 [bt][y][32]; v bf16 [bt][y][128].
// attn_out fp32 [bt][64][64]; av bf16 [bt][y][128].
// ---------------------------------------------------------------------------
__global__ __launch_bounds__(256) void attention(
    const float* __restrict__ q,
    const float* __restrict__ k,
    const ushort* __restrict__ v,
    float* __restrict__ attn_out,
    ushort* __restrict__ av)
{
    const int bt  = blockIdx.x;
    const int tid = threadIdx.x;

    __shared__ float qs[64][33];
    __shared__ float ks[64][33];
    __shared__ float S[64][65];
    __shared__ float vs[64][128];

    const float* qb = q + (size_t)bt * 64 * 32;
    const float* kb = k + (size_t)bt * 64 * 32;
    for (int i = tid; i < 64 * 32; i += 256) {
        qs[i >> 5][i & 31] = qb[i];
        ks[i >> 5][i & 31] = kb[i];
    }
    const ushort* vb = v + (size_t)bt * 64 * 128;
    for (int i = tid; i < 64 * 128; i += 256) {
        ushort u = vb[i];
        bf16 h = *(bf16*)&u;
        vs[i >> 7][i & 127] = __bfloat162float(h);
    }
    __syncthreads();

    for (int idx = tid; idx < 4096; idx += 256) {
        const int i = idx >> 6, j = idx & 63;
        float s = 0.f;
#pragma unroll
        for (int c = 0; c < 32; ++c) s += qs[i][c] * ks[j][c];
        S[i][j] = s;
    }
    __syncthreads();

    {
        const int row = tid >> 2, sub = tid & 3;
        float m = -INFINITY;
#pragma unroll
        for (int jj = 0; jj < 16; ++jj) m = fmaxf(m, S[row][sub * 16 + jj]);
        m = fmaxf(m, __shfl_xor(m, 1));
        m = fmaxf(m, __shfl_xor(m, 2));
        float e[16], sum = 0.f;
#pragma unroll
        for (int jj = 0; jj < 16; ++jj) {
            e[jj] = expf(S[row][sub * 16 + jj] - m);
            sum += e[jj];
        }
        sum += __shfl_xor(sum, 1);
        sum += __shfl_xor(sum, 2);
        const float inv = 1.f / sum;
#pragma unroll
        for (int jj = 0; jj < 16; ++jj) S[row][sub * 16 + jj] = e[jj] * inv;
    }
    __syncthreads();

    float* ao = attn_out + (size_t)bt * 4096;
    for (int idx = tid; idx < 4096; idx += 256)
        ao[idx] = S[idx >> 6][idx & 63];

    {
        const int i = tid & 63, quad = tid >> 6;
        float acc[32];
#pragma unroll
        for (int cc = 0; cc < 32; ++cc) acc[cc] = 0.f;
        for (int j = 0; j < 64; ++j) {
            const float s = S[i][j];
#pragma unroll
            for (int cc = 0; cc < 32; ++cc)
                acc[cc] += s * vs[j][quad * 32 + cc];
        }
        ushort* avb = av + (size_t)bt * 64 * 128 + (size_t)i * 128 + quad * 32;
#pragma unroll
        for (int cc = 0; cc < 32; ++cc) avb[cc] = f2bf(acc[cc]);
    }
}

// ---------------------------------------------------------------------------
// out_conv_mfma: block=(b,y,mt): M=128 oc, N=64 t, K=128ci*9tap.
// B-tile LDS [3 dy][66 tl][128 ci] from av, single stage. out fp32 + residual.
// ---------------------------------------------------------------------------
__global__ __launch_bounds__(256) void out_conv_mfma(
    const float* __restrict__ x,
    const ushort* __restrict__ av,
    const ushort* __restrict__ woT,
    const float* __restrict__ sigma,
    float* __restrict__ out)
{
    const int mt   = blockIdx.x & 1;
    const int y    = (blockIdx.x >> 1) & 63;
    const int b    = blockIdx.x >> 7;
    const int tid  = threadIdx.x;
    const int lane = tid & 63;
    const int w    = tid >> 6;

    __shared__ ushort btile[3 * 66 * 128];

    f32x4 acc[2][4];
#pragma unroll
    for (int m = 0; m < 2; ++m)
#pragma unroll
        for (int nf = 0; nf < 4; ++nf) acc[m][nf] = (f32x4){0.f, 0.f, 0.f, 0.f};

    for (int idx = tid; idx < 198 * 16; idx += 256) {
        const int row = idx >> 4, ch = idx & 15;
        const int dy = row / 66, tl = row % 66;
        const int yp = y + dy - 1, tp = tl - 1;
        int4 val = {0, 0, 0, 0};
        if ((unsigned)yp < 64u && (unsigned)tp < 64u)
            val = *(const int4*)(av + ((((size_t)b * 64 + tp) * 64 + yp) * 128 + ch * 8));
        const int byte_off = row * 256 + ((ch * 16) ^ ((row & 7) << 4));
        *(int4*)((char*)btile + byte_off) = val;
    }
    __syncthreads();

#pragma unroll
    for (int tap = 0; tap < 9; ++tap) {
        const int dy = tap / 3, dx = tap % 3;
#pragma unroll
        for (int kk = 0; kk < 4; ++kk) {
            s16x8 bf[4];
#pragma unroll
            for (int nf = 0; nf < 4; ++nf) {
                const int tl = nf * 16 + (lane & 15) + dx;
                const int row = dy * 66 + tl;
                const int bir = kk * 64 + (lane >> 4) * 16;
                bf[nf] = *(const s16x8*)((const char*)btile + row * 256 + (bir ^ ((row & 7) << 4)));
            }
#pragma unroll
            for (int m = 0; m < 2; ++m) {
                const int oc = mt * 128 + w * 32 + m * 16 + (lane & 15);
                s16x8 af = *(const s16x8*)(woT + (size_t)(tap * 256 + oc) * 128 + kk * 32 + (lane >> 4) * 8);
#pragma unroll
                for (int nf = 0; nf < 4; ++nf)
                    acc[m][nf] = __builtin_amdgcn_mfma_f32_16x16x32_bf16(af, bf[nf], acc[m][nf], 0, 0, 0);
            }
        }
    }

    const float s = sigma[0];
#pragma unroll
    for (int m = 0; m < 2; ++m)
#pragma unroll
        for (int nf = 0; nf < 4; ++nf)
#pragma unroll
            for (int r = 0; r < 4; ++r) {
                const int oc = mt * 128 + w * 32 + m * 16 + (lane >> 4) * 4 + r;
                const int t  = nf * 16 + (lane & 15);
                const size_t a = (((size_t)b * 256 + oc) * 64 + y) * 64 + t;
                out[a] = x[a] + s * acc[m][nf][r];
            }
}

// ---------------------------------------------------------------------------
extern "C" void kernel_launch(void* const* d_in, const int* in_sizes, int n_in,
                              void* d_out, int out_size, void* d_ws, size_t ws_size,
                              hipStream_t stream)
{
    const float* x     = (const float*)d_in[0];
    const float* wq    = (const float*)d_in[1];
    const float* wk    = (const float*)d_in[2];
    const float* wv    = (const float*)d_in[3];
    const float* wo    = (const float*)d_in[4];
    const float* sigma = (const float*)d_in[5];

    float* out      = (float*)d_out;                 // [16,256,64,64] = 16,777,216 f
    float* attn_out = out + (size_t)B_ * CIN * P;    // [1024,64,64]   =  4,194,304 f

    // Scratch aliased into the out region (dead until out_conv_mfma runs):
    ushort* xT = (ushort*)out;                       // 16,777,216 bf16 = 33.5 MB
    float*  q  = (float*)(xT + (size_t)16777216);    // 2,097,152 f = 8 MB
    float*  k  = q + 2097152;                        // 8 MB  (total 49.5 MB < 64 MB)

    // d_ws:
    ushort* v   = (ushort*)d_ws;                     // 8,388,608 bf16 = 16.8 MB
    ushort* av  = v + 8388608;                       // 16.8 MB
    ushort* wvT = av + 8388608;                      // 294,912 bf16
    ushort* woT = wvT + 294912;                      // 294,912 bf16

    repack_w<<<(2 * 294912 + 255) / 256, 256, 0, stream>>>(wv, wo, wvT, woT);
    repack_x<<<B_ * VDIM, 256, 0, stream>>>(x, xT);
    qk_conv<<<B_ * 8 * (P / 256), 256, 0, stream>>>(x, wq, wk, q, k);
    v_conv<<<B_ * TDIM, 256, 0, stream>>>(xT, wvT, v);
    attention<<<B_ * TDIM, 256, 0, stream>>>(q, k, v, attn_out, av);
    out_conv_mfma<<<B_ * VDIM * 2, 256, 0, stream>>>(x, av, woT, sigma, out);
}

// Round 3
// 533.636 us; speedup vs baseline: 11.6709x; 1.2482x over previous
//
#include <hip/hip_runtime.h>
#include <hip/hip_bf16.h>

typedef __hip_bfloat16 bf16;
typedef float f32x4 __attribute__((ext_vector_type(4)));
typedef short s16x8 __attribute__((ext_vector_type(8)));

#define B_   16
#define CIN  256
#define CQK  32
#define CV   128
#define VDIM 64
#define TDIM 64
#define P    (VDIM * TDIM)   // 4096

static __device__ __forceinline__ ushort f2bf(float f) {
    bf16 h = __float2bfloat16(f);
    return *(ushort*)&h;
}
static __device__ __forceinline__ float bf2f(ushort u) {
    bf16 h = *(bf16*)&u;
    return __bfloat162float(h);
}

// ---------------------------------------------------------------------------
// repack_w:
//  wq,wk [32][256][3][3] f32 -> wqkT_hi/lo [9][64][256] bf16 (oc<32 q, else k)
//  wv [128][256][3][3] -> wvT [9][128][256] bf16
//  wo [256][128][3][3] -> woT [9][256][128] bf16
// ---------------------------------------------------------------------------
__global__ __launch_bounds__(256) void repack_w(
    const float* __restrict__ wq, const float* __restrict__ wk,
    const float* __restrict__ wv, const float* __restrict__ wo,
    ushort* __restrict__ wvT, ushort* __restrict__ woT,
    ushort* __restrict__ wqh, ushort* __restrict__ wql)
{
    int i = blockIdx.x * 256 + threadIdx.x;
    const int NQK = 9 * 64 * 256;      // 147456
    const int NV  = 9 * 128 * 256;     // 294912
    if (i < NQK) {
        int tap = i / (64 * 256);
        int r   = i % (64 * 256);
        int oc  = r >> 8;
        int ci  = r & 255;
        const float* src = (oc < 32) ? wq : wk;
        float f = src[(size_t)(oc & 31) * 2304 + ci * 9 + tap];
        ushort h = f2bf(f);
        wqh[i] = h;
        wql[i] = f2bf(f - bf2f(h));
    } else if (i < NQK + NV) {
        i -= NQK;
        int tap = i / (128 * 256);
        int r   = i % (128 * 256);
        int oc  = r >> 8;
        int ci  = r & 255;
        wvT[i] = f2bf(wv[(size_t)oc * 2304 + ci * 9 + tap]);
    } else {
        i -= NQK + NV;
        int tap = i / (256 * 128);
        int r   = i % (256 * 128);
        int oc  = r >> 7;
        int ci  = r & 127;
        woT[i] = f2bf(wo[(size_t)oc * 1152 + ci * 9 + tap]);
    }
}

// ---------------------------------------------------------------------------
// repack_x: x [B][256][64y][64t] f32 -> dst [B][64t][64y][256ci] bf16
// lo_mode=0: dst = bf16(x) ; lo_mode=1: dst = bf16(x - bf16(x))
// ---------------------------------------------------------------------------
__global__ __launch_bounds__(256) void repack_x(
    const float* __restrict__ x, ushort* __restrict__ dst, int lo_mode)
{
    const int b = blockIdx.x >> 6;
    const int y = blockIdx.x & 63;
    __shared__ ushort tile[64][257];
    const int t  = threadIdx.x & 63;
    const int cq = threadIdx.x >> 6;
    const float* xb = x + (((size_t)b * CIN) * VDIM + y) * TDIM;
    for (int ci = cq; ci < 256; ci += 4) {
        float f = xb[(size_t)ci * P + t];
        ushort h = f2bf(f);
        tile[t][ci] = lo_mode ? f2bf(f - bf2f(h)) : h;
    }
    __syncthreads();
    const int ci4 = (threadIdx.x & 63) * 4;
    const int tr0 = threadIdx.x >> 6;
    for (int tr = tr0; tr < 64; tr += 4) {
        ushort4 u;
        u.x = tile[tr][ci4]; u.y = tile[tr][ci4 + 1];
        u.z = tile[tr][ci4 + 2]; u.w = tile[tr][ci4 + 3];
        *(ushort4*)(dst + ((((size_t)b * 64 + tr) * 64 + y) * 256 + ci4)) = u;
    }
}

// Stage one [3 dx][66 yl][128 ci] bf16 halo tile into swizzled LDS.
#define STAGE_TILE(SRC, CI0)                                                      \
    for (int idx = tid; idx < 198 * 16; idx += 256) {                             \
        const int row = idx >> 4, ch = idx & 15;                                  \
        const int dxs = row / 66, yl = row % 66;                                  \
        const int tp = t0 + dxs - 1, yp = yl - 1;                                 \
        int4 val = {0, 0, 0, 0};                                                  \
        if ((unsigned)tp < 64u && (unsigned)yp < 64u)                             \
            val = *(const int4*)((SRC) + ((((size_t)b * 64 + tp) * 64 + yp) * 256 \
                                          + (CI0) + ch * 8));                     \
        const int byte_off = row * 256 + ((ch * 16) ^ ((row & 7) << 4));          \
        *(int4*)((char*)btile + byte_off) = val;                                  \
    }

// ---------------------------------------------------------------------------
// qk_mfma: split-bf16 3-pass implicit-GEMM conv for q and k.
// block=(b,t0): M=64 (32 q-oc | 32 k-oc), N=64 y, K=256ci*9tap.
// q,k out fp32 [b][t][y][32].
// ---------------------------------------------------------------------------
__global__ __launch_bounds__(256) void qk_mfma(
    const ushort* __restrict__ xh, const ushort* __restrict__ xl,
    const ushort* __restrict__ wqh, const ushort* __restrict__ wql,
    float* __restrict__ qo, float* __restrict__ ko)
{
    const int b    = blockIdx.x >> 6;
    const int t0   = blockIdx.x & 63;
    const int tid  = threadIdx.x;
    const int lane = tid & 63;
    const int w    = tid >> 6;
    const int oc   = w * 16 + (lane & 15);   // combined q|k channel

    __shared__ ushort btile[3 * 66 * 128];

    f32x4 acc[4];
#pragma unroll
    for (int nf = 0; nf < 4; ++nf) acc[nf] = (f32x4){0.f, 0.f, 0.f, 0.f};

    for (int chunk = 0; chunk < 2; ++chunk) {
        const int ci0 = chunk * 128;

        // ---- x_hi tile: passes w_hi*x_hi and w_lo*x_hi ----
        __syncthreads();
        STAGE_TILE(xh, ci0)
        __syncthreads();
#pragma unroll
        for (int tap = 0; tap < 9; ++tap) {
            const int dy = tap / 3, dxp = tap % 3;
#pragma unroll
            for (int kk = 0; kk < 4; ++kk) {
                s16x8 bfr[4];
#pragma unroll
                for (int nf = 0; nf < 4; ++nf) {
                    const int yl = nf * 16 + (lane & 15) + dy;
                    const int row = dxp * 66 + yl;
                    const int bir = kk * 64 + (lane >> 4) * 16;
                    bfr[nf] = *(const s16x8*)((const char*)btile + row * 256 + (bir ^ ((row & 7) << 4)));
                }
                const size_t aoff = (size_t)(tap * 64 + oc) * 256 + ci0 + kk * 32 + (lane >> 4) * 8;
                s16x8 ah = *(const s16x8*)(wqh + aoff);
                s16x8 al = *(const s16x8*)(wql + aoff);
#pragma unroll
                for (int nf = 0; nf < 4; ++nf)
                    acc[nf] = __builtin_amdgcn_mfma_f32_16x16x32_bf16(ah, bfr[nf], acc[nf], 0, 0, 0);
#pragma unroll
                for (int nf = 0; nf < 4; ++nf)
                    acc[nf] = __builtin_amdgcn_mfma_f32_16x16x32_bf16(al, bfr[nf], acc[nf], 0, 0, 0);
            }
        }

        // ---- x_lo tile: pass w_hi*x_lo ----
        __syncthreads();
        STAGE_TILE(xl, ci0)
        __syncthreads();
#pragma unroll
        for (int tap = 0; tap < 9; ++tap) {
            const int dy = tap / 3, dxp = tap % 3;
#pragma unroll
            for (int kk = 0; kk < 4; ++kk) {
                s16x8 bfr[4];
#pragma unroll
                for (int nf = 0; nf < 4; ++nf) {
                    const int yl = nf * 16 + (lane & 15) + dy;
                    const int row = dxp * 66 + yl;
                    const int bir = kk * 64 + (lane >> 4) * 16;
                    bfr[nf] = *(const s16x8*)((const char*)btile + row * 256 + (bir ^ ((row & 7) << 4)));
                }
                const size_t aoff = (size_t)(tap * 64 + oc) * 256 + ci0 + kk * 32 + (lane >> 4) * 8;
                s16x8 ah = *(const s16x8*)(wqh + aoff);
#pragma unroll
                for (int nf = 0; nf < 4; ++nf)
                    acc[nf] = __builtin_amdgcn_mfma_f32_16x16x32_bf16(ah, bfr[nf], acc[nf], 0, 0, 0);
            }
        }
    }

    float* o = (w < 2) ? qo : ko;
    const int oc4 = (w & 1) * 16 + (lane >> 4) * 4;
#pragma unroll
    for (int nf = 0; nf < 4; ++nf) {
        const int yy = nf * 16 + (lane & 15);
        *(f32x4*)(o + ((((size_t)b * 64 + t0) * 64 + yy) * 32 + oc4)) = acc[nf];
    }
}

// ---------------------------------------------------------------------------
// vattn: fused v-conv (MFMA implicit GEMM) + attention.
// block=(b,t0): v = conv(x)[128 oc][64 y]; then S=qk^T, softmax, attn write,
// AV, av write. q,k fp32 [b][t][y][32]; attn fp32 [bt][64][64];
// av bf16 [b][t][y][128].
// ---------------------------------------------------------------------------
__global__ __launch_bounds__(256) void vattn(
    const ushort* __restrict__ xh,
    const ushort* __restrict__ wvT,
    const float* __restrict__ q,
    const float* __restrict__ k,
    float* __restrict__ attn_out,
    ushort* __restrict__ av)
{
    const int b    = blockIdx.x >> 6;
    const int t0   = blockIdx.x & 63;
    const int tid  = threadIdx.x;
    const int lane = tid & 63;
    const int w    = tid >> 6;

    __shared__ __align__(16) char smem[50688];
    ushort* btile = (ushort*)smem;

    f32x4 acc[2][4];
#pragma unroll
    for (int m = 0; m < 2; ++m)
#pragma unroll
        for (int nf = 0; nf < 4; ++nf) acc[m][nf] = (f32x4){0.f, 0.f, 0.f, 0.f};

    for (int chunk = 0; chunk < 2; ++chunk) {
        const int ci0 = chunk * 128;
        __syncthreads();
        STAGE_TILE(xh, ci0)
        __syncthreads();
#pragma unroll
        for (int tap = 0; tap < 9; ++tap) {
            const int dy = tap / 3, dxp = tap % 3;
#pragma unroll
            for (int kk = 0; kk < 4; ++kk) {
                s16x8 bfr[4];
#pragma unroll
                for (int nf = 0; nf < 4; ++nf) {
                    const int yl = nf * 16 + (lane & 15) + dy;
                    const int row = dxp * 66 + yl;
                    const int bir = kk * 64 + (lane >> 4) * 16;
                    bfr[nf] = *(const s16x8*)((const char*)btile + row * 256 + (bir ^ ((row & 7) << 4)));
                }
#pragma unroll
                for (int m = 0; m < 2; ++m) {
                    const int oc = w * 32 + m * 16 + (lane & 15);
                    s16x8 af = *(const s16x8*)(wvT + (size_t)(tap * 128 + oc) * 256 + ci0 + kk * 32 + (lane >> 4) * 8);
#pragma unroll
                    for (int nf = 0; nf < 4; ++nf)
                        acc[m][nf] = __builtin_amdgcn_mfma_f32_16x16x32_bf16(af, bfr[nf], acc[m][nf], 0, 0, 0);
                }
            }
        }
    }
    __syncthreads();   // btile dead; repurpose LDS for attention

    float (*qs)[33]  = (float(*)[33])smem;                 //     0 ..  8448
    float (*ks)[33]  = (float(*)[33])(smem + 8448);        //  8448 .. 16896
    float (*S)[65]   = (float(*)[65])(smem + 16896);       // 16896 .. 33536
    ushort (*vs)[132] = (ushort(*)[132])(smem + 33536);    // 33536 .. 50432

    // v (bf16) -> vs
#pragma unroll
    for (int m = 0; m < 2; ++m)
#pragma unroll
        for (int nf = 0; nf < 4; ++nf) {
            const int yy = nf * 16 + (lane & 15);
            const int c0 = w * 32 + m * 16 + (lane >> 4) * 4;
            ushort4 u;
            u.x = f2bf(acc[m][nf][0]); u.y = f2bf(acc[m][nf][1]);
            u.z = f2bf(acc[m][nf][2]); u.w = f2bf(acc[m][nf][3]);
            *(ushort4*)&vs[yy][c0] = u;
        }
    // q,k -> LDS
    const float* qb = q + (size_t)blockIdx.x * 2048;
    const float* kb = k + (size_t)blockIdx.x * 2048;
    for (int i = tid; i < 2048; i += 256) {
        qs[i >> 5][i & 31] = qb[i];
        ks[i >> 5][i & 31] = kb[i];
    }
    __syncthreads();

    // S = q k^T
    for (int idx = tid; idx < 4096; idx += 256) {
        const int i = idx >> 6, j = idx & 63;
        float s = 0.f;
#pragma unroll
        for (int c = 0; c < 32; ++c) s += qs[i][c] * ks[j][c];
        S[i][j] = s;
    }
    __syncthreads();

    // softmax rows: 4 lanes/row
    {
        const int row = tid >> 2, sub = tid & 3;
        float m = -INFINITY;
#pragma unroll
        for (int jj = 0; jj < 16; ++jj) m = fmaxf(m, S[row][sub * 16 + jj]);
        m = fmaxf(m, __shfl_xor(m, 1));
        m = fmaxf(m, __shfl_xor(m, 2));
        float e[16], sum = 0.f;
#pragma unroll
        for (int jj = 0; jj < 16; ++jj) {
            e[jj] = expf(S[row][sub * 16 + jj] - m);
            sum += e[jj];
        }
        sum += __shfl_xor(sum, 1);
        sum += __shfl_xor(sum, 2);
        const float inv = 1.f / sum;
#pragma unroll
        for (int jj = 0; jj < 16; ++jj) S[row][sub * 16 + jj] = e[jj] * inv;
    }
    __syncthreads();

    // attn write
    float* ao = attn_out + (size_t)blockIdx.x * 4096;
    for (int idx = tid; idx < 4096; idx += 256)
        ao[idx] = S[idx >> 6][idx & 63];

    // AV
    {
        const int i = tid & 63, quad = tid >> 6;
        float fa[32];
#pragma unroll
        for (int cc = 0; cc < 32; ++cc) fa[cc] = 0.f;
        for (int j = 0; j < 64; ++j) {
            const float s = S[i][j];
#pragma unroll
            for (int cc = 0; cc < 32; ++cc)
                fa[cc] += s * bf2f(vs[j][quad * 32 + cc]);
        }
        ushort* avb = av + (size_t)blockIdx.x * 8192 + (size_t)i * 128 + quad * 32;
#pragma unroll
        for (int cc = 0; cc < 32; ++cc) avb[cc] = f2bf(fa[cc]);
    }
}

// ---------------------------------------------------------------------------
// out_conv_mfma: block=(b,y,mt): M=128 oc, N=64 t, K=128ci*9tap.
// ---------------------------------------------------------------------------
__global__ __launch_bounds__(256) void out_conv_mfma(
    const float* __restrict__ x,
    const ushort* __restrict__ av,
    const ushort* __restrict__ woT,
    const float* __restrict__ sigma,
    float* __restrict__ out)
{
    const int mt   = blockIdx.x & 1;
    const int y    = (blockIdx.x >> 1) & 63;
    const int b    = blockIdx.x >> 7;
    const int tid  = threadIdx.x;
    const int lane = tid & 63;
    const int w    = tid >> 6;

    __shared__ ushort btile[3 * 66 * 128];

    f32x4 acc[2][4];
#pragma unroll
    for (int m = 0; m < 2; ++m)
#pragma unroll
        for (int nf = 0; nf < 4; ++nf) acc[m][nf] = (f32x4){0.f, 0.f, 0.f, 0.f};

    for (int idx = tid; idx < 198 * 16; idx += 256) {
        const int row = idx >> 4, ch = idx & 15;
        const int dy = row / 66, tl = row % 66;
        const int yp = y + dy - 1, tp = tl - 1;
        int4 val = {0, 0, 0, 0};
        if ((unsigned)yp < 64u && (unsigned)tp < 64u)
            val = *(const int4*)(av + ((((size_t)b * 64 + tp) * 64 + yp) * 128 + ch * 8));
        const int byte_off = row * 256 + ((ch * 16) ^ ((row & 7) << 4));
        *(int4*)((char*)btile + byte_off) = val;
    }
    __syncthreads();

#pragma unroll
    for (int tap = 0; tap < 9; ++tap) {
        const int dy = tap / 3, dxp = tap % 3;
#pragma unroll
        for (int kk = 0; kk < 4; ++kk) {
            s16x8 bfr[4];
#pragma unroll
            for (int nf = 0; nf < 4; ++nf) {
                const int tl = nf * 16 + (lane & 15) + dxp;
                const int row = dy * 66 + tl;
                const int bir = kk * 64 + (lane >> 4) * 16;
                bfr[nf] = *(const s16x8*)((const char*)btile + row * 256 + (bir ^ ((row & 7) << 4)));
            }
#pragma unroll
            for (int m = 0; m < 2; ++m) {
                const int oc = mt * 128 + w * 32 + m * 16 + (lane & 15);
                s16x8 af = *(const s16x8*)(woT + (size_t)(tap * 256 + oc) * 128 + kk * 32 + (lane >> 4) * 8);
#pragma unroll
                for (int nf = 0; nf < 4; ++nf)
                    acc[m][nf] = __builtin_amdgcn_mfma_f32_16x16x32_bf16(af, bfr[nf], acc[m][nf], 0, 0, 0);
            }
        }
    }

    const float s = sigma[0];
#pragma unroll
    for (int m = 0; m < 2; ++m)
#pragma unroll
        for (int nf = 0; nf < 4; ++nf)
#pragma unroll
            for (int r = 0; r < 4; ++r) {
                const int oc = mt * 128 + w * 32 + m * 16 + (lane >> 4) * 4 + r;
                const int t  = nf * 16 + (lane & 15);
                const size_t a = (((size_t)b * 256 + oc) * 64 + y) * 64 + t;
                out[a] = x[a] + s * acc[m][nf][r];
            }
}

// ---------------------------------------------------------------------------
extern "C" void kernel_launch(void* const* d_in, const int* in_sizes, int n_in,
                              void* d_out, int out_size, void* d_ws, size_t ws_size,
                              hipStream_t stream)
{
    const float* x     = (const float*)d_in[0];
    const float* wq    = (const float*)d_in[1];
    const float* wk    = (const float*)d_in[2];
    const float* wv    = (const float*)d_in[3];
    const float* wo    = (const float*)d_in[4];
    const float* sigma = (const float*)d_in[5];

    float* out      = (float*)d_out;                 // [16,256,64,64]
    float* attn_out = out + (size_t)16777216;        // [1024,64,64]

    // x hi/lo bf16 alias the out-image region (dead until out_conv_mfma):
    ushort* xh = (ushort*)d_out;                     // 16,777,216 bf16 = 32 MiB
    ushort* xl = xh + (size_t)16777216;              // 32 MiB (ends at attn_out)

    // d_ws: av | q | k | weights  (~33.7 MiB)
    ushort* av  = (ushort*)d_ws;                     // 8,388,608 bf16
    float*  q   = (float*)(av + 8388608);            // 2,097,152 f
    float*  k   = q + 2097152;                       // 2,097,152 f
    ushort* wvT = (ushort*)(k + 2097152);            // 294,912
    ushort* woT = wvT + 294912;                      // 294,912
    ushort* wqh = woT + 294912;                      // 147,456
    ushort* wql = wqh + 147456;                      // 147,456

    repack_w<<<2880, 256, 0, stream>>>(wq, wk, wv, wo, wvT, woT, wqh, wql);
    repack_x<<<B_ * VDIM, 256, 0, stream>>>(x, xh, 0);
    repack_x<<<B_ * VDIM, 256, 0, stream>>>(x, xl, 1);
    qk_mfma<<<B_ * TDIM, 256, 0, stream>>>(xh, xl, wqh, wql, q, k);
    vattn<<<B_ * TDIM, 256, 0, stream>>>(xh, wvT, q, k, attn_out, av);
    out_conv_mfma<<<B_ * VDIM * 2, 256, 0, stream>>>(x, av, woT, sigma, out);
}

// Round 4
// 435.604 us; speedup vs baseline: 14.2974x; 1.2250x over previous
//
#include <hip/hip_runtime.h>
#include <hip/hip_bf16.h>

typedef __hip_bfloat16 bf16;
typedef float f32x4 __attribute__((ext_vector_type(4)));
typedef short s16x8 __attribute__((ext_vector_type(8)));

#define B_   16
#define CIN  256
#define CQK  32
#define CV   128
#define VDIM 64
#define TDIM 64
#define P    (VDIM * TDIM)   // 4096

static __device__ __forceinline__ ushort f2bf(float f) {
    bf16 h = __float2bfloat16(f);
    return *(ushort*)&h;
}
static __device__ __forceinline__ float bf2f(ushort u) {
    bf16 h = *(bf16*)&u;
    return __bfloat162float(h);
}

// ---------------------------------------------------------------------------
// repack_w:
//  wq,wk [32][256][3][3] f32 -> wqh/wql [9][64][256] bf16 hi/lo (oc<32 q else k)
//  wv [128][256][3][3] -> wvT [9][128][256] bf16
//  wo [256][128][3][3] -> woT [9][256][128] bf16
// ---------------------------------------------------------------------------
__global__ __launch_bounds__(256) void repack_w(
    const float* __restrict__ wq, const float* __restrict__ wk,
    const float* __restrict__ wv, const float* __restrict__ wo,
    ushort* __restrict__ wvT, ushort* __restrict__ woT,
    ushort* __restrict__ wqh, ushort* __restrict__ wql)
{
    int i = blockIdx.x * 256 + threadIdx.x;
    const int NQK = 9 * 64 * 256;      // 147456
    const int NV  = 9 * 128 * 256;     // 294912
    if (i < NQK) {
        int tap = i / (64 * 256);
        int r   = i % (64 * 256);
        int oc  = r >> 8;
        int ci  = r & 255;
        const float* src = (oc < 32) ? wq : wk;
        float f = src[(size_t)(oc & 31) * 2304 + ci * 9 + tap];
        ushort h = f2bf(f);
        wqh[i] = h;
        wql[i] = f2bf(f - bf2f(h));
    } else if (i < NQK + NV) {
        i -= NQK;
        int tap = i / (128 * 256);
        int r   = i % (128 * 256);
        int oc  = r >> 8;
        int ci  = r & 255;
        wvT[i] = f2bf(wv[(size_t)oc * 2304 + ci * 9 + tap]);
    } else {
        i -= NQK + NV;
        int tap = i / (256 * 128);
        int r   = i % (256 * 128);
        int oc  = r >> 7;
        int ci  = r & 127;
        woT[i] = f2bf(wo[(size_t)oc * 1152 + ci * 9 + tap]);
    }
}

// ---------------------------------------------------------------------------
// repack_x2: x [B][256][64y][64t] f32 -> xh,xl [B][64t][64y][256ci] bf16
// (hi = bf16(x), lo = bf16(x - hi)) in ONE pass over x.
// ---------------------------------------------------------------------------
__global__ __launch_bounds__(256) void repack_x2(
    const float* __restrict__ x, ushort* __restrict__ xhd, ushort* __restrict__ xld)
{
    const int b = blockIdx.x >> 6;
    const int y = blockIdx.x & 63;
    __shared__ ushort th[64][257];
    __shared__ ushort tl_[64][257];
    const int t  = threadIdx.x & 63;
    const int cq = threadIdx.x >> 6;
    const float* xb = x + (((size_t)b * CIN) * VDIM + y) * TDIM;
    for (int ci = cq; ci < 256; ci += 4) {
        float f = xb[(size_t)ci * P + t];
        ushort h = f2bf(f);
        th[t][ci]  = h;
        tl_[t][ci] = f2bf(f - bf2f(h));
    }
    __syncthreads();
    const int ci4 = (threadIdx.x & 63) * 4;
    const int tr0 = threadIdx.x >> 6;
    for (int tr = tr0; tr < 64; tr += 4) {
        ushort4 uh, ul;
        uh.x = th[tr][ci4];     uh.y = th[tr][ci4 + 1];
        uh.z = th[tr][ci4 + 2]; uh.w = th[tr][ci4 + 3];
        ul.x = tl_[tr][ci4];     ul.y = tl_[tr][ci4 + 1];
        ul.z = tl_[tr][ci4 + 2]; ul.w = tl_[tr][ci4 + 3];
        const size_t o = ((((size_t)b * 64 + tr) * 64 + y) * 256 + ci4);
        *(ushort4*)(xhd + o) = uh;
        *(ushort4*)(xld + o) = ul;
    }
}

// Stage one [3 dx][66 yl][128 ci] bf16 halo tile into swizzled LDS.
#define STAGE_TILE(SRC, CI0)                                                      \
    for (int idx = tid; idx < 198 * 16; idx += 256) {                             \
        const int row = idx >> 4, ch = idx & 15;                                  \
        const int dxs = row / 66, yl = row % 66;                                  \
        const int tp = t0 + dxs - 1, yp = yl - 1;                                 \
        int4 val = {0, 0, 0, 0};                                                  \
        if ((unsigned)tp < 64u && (unsigned)yp < 64u)                             \
            val = *(const int4*)((SRC) + ((((size_t)b * 64 + tp) * 64 + yp) * 256 \
                                          + (CI0) + ch * 8));                     \
        const int byte_off = row * 256 + ((ch * 16) ^ ((row & 7) << 4));          \
        *(int4*)((char*)btile + byte_off) = val;                                  \
    }

// Read the 4 B-fragments for one tap (dy,dxp) at k-step kk.
#define READ_BFR(BFR, DY, DXP, KK)                                                \
    {                                                                             \
        _Pragma("unroll")                                                         \
        for (int nf = 0; nf < 4; ++nf) {                                          \
            const int yl = nf * 16 + (lane & 15) + (DY);                          \
            const int row = (DXP) * 66 + yl;                                      \
            const int bir = (KK) * 64 + (lane >> 4) * 16;                         \
            BFR[nf] = *(const s16x8*)((const char*)btile + row * 256 +            \
                                      (bir ^ ((row & 7) << 4)));                  \
        }                                                                         \
    }

// ---------------------------------------------------------------------------
// qkvattn: fused q/k/v 3x3 conv (MFMA implicit GEMM) + attention per (b,t0).
//  v: 128 oc bf16-weight 1-pass; q,k: 32+32 oc split-bf16 3-pass (fp32-accurate).
//  Then S=qk^T (fp32 VALU), softmax, attn write, AV, av write.
// ---------------------------------------------------------------------------
__global__ __launch_bounds__(256, 2) void qkvattn(
    const ushort* __restrict__ xh, const ushort* __restrict__ xl,
    const ushort* __restrict__ wvT,
    const ushort* __restrict__ wqh, const ushort* __restrict__ wql,
    float* __restrict__ attn_out, ushort* __restrict__ av)
{
    // XCD-bijective swizzle (1024 blocks, 8 XCDs, 128/XCD)
    const int bid  = ((blockIdx.x & 7) << 7) | (blockIdx.x >> 3);
    const int b    = bid >> 6;
    const int t0   = bid & 63;
    const int tid  = threadIdx.x;
    const int lane = tid & 63;
    const int w    = tid >> 6;

    __shared__ __align__(16) char smem[50688];
    ushort* btile = (ushort*)smem;

    f32x4 accv[2][4];
    f32x4 accq[4];
#pragma unroll
    for (int m = 0; m < 2; ++m)
#pragma unroll
        for (int nf = 0; nf < 4; ++nf) accv[m][nf] = (f32x4){0.f, 0.f, 0.f, 0.f};
#pragma unroll
    for (int nf = 0; nf < 4; ++nf) accq[nf] = (f32x4){0.f, 0.f, 0.f, 0.f};

    const int ocv  = w * 32 + (lane & 15);        // v channel base (m adds 16)
    const int ocqk = w * 16 + (lane & 15);        // combined q|k channel

    for (int chunk = 0; chunk < 2; ++chunk) {
        const int ci0 = chunk * 128;

        __syncthreads();
        STAGE_TILE(xh, ci0)
        __syncthreads();

        // ---- v pass (wv · x_hi) ----
        for (int kk = 0; kk < 4; ++kk) {
            s16x8 wv_[9][2];
#pragma unroll
            for (int tap = 0; tap < 9; ++tap)
#pragma unroll
                for (int m = 0; m < 2; ++m)
                    wv_[tap][m] = *(const s16x8*)(wvT + (size_t)(tap * 128 + ocv + m * 16) * 256
                                                  + ci0 + kk * 32 + (lane >> 4) * 8);
#pragma unroll
            for (int tap = 0; tap < 9; ++tap) {
                s16x8 bfr[4];
                READ_BFR(bfr, tap / 3, tap % 3, kk)
#pragma unroll
                for (int m = 0; m < 2; ++m)
#pragma unroll
                    for (int nf = 0; nf < 4; ++nf)
                        accv[m][nf] = __builtin_amdgcn_mfma_f32_16x16x32_bf16(wv_[tap][m], bfr[nf], accv[m][nf], 0, 0, 0);
            }
        }

        // ---- qk hi pass (w_hi·x_hi + w_lo·x_hi) ----
        for (int kk = 0; kk < 4; ++kk) {
            s16x8 ah[9], al[9];
#pragma unroll
            for (int tap = 0; tap < 9; ++tap) {
                const size_t aoff = (size_t)(tap * 64 + ocqk) * 256 + ci0 + kk * 32 + (lane >> 4) * 8;
                ah[tap] = *(const s16x8*)(wqh + aoff);
                al[tap] = *(const s16x8*)(wql + aoff);
            }
#pragma unroll
            for (int tap = 0; tap < 9; ++tap) {
                s16x8 bfr[4];
                READ_BFR(bfr, tap / 3, tap % 3, kk)
#pragma unroll
                for (int nf = 0; nf < 4; ++nf)
                    accq[nf] = __builtin_amdgcn_mfma_f32_16x16x32_bf16(ah[tap], bfr[nf], accq[nf], 0, 0, 0);
#pragma unroll
                for (int nf = 0; nf < 4; ++nf)
                    accq[nf] = __builtin_amdgcn_mfma_f32_16x16x32_bf16(al[tap], bfr[nf], accq[nf], 0, 0, 0);
            }
        }

        __syncthreads();
        STAGE_TILE(xl, ci0)
        __syncthreads();

        // ---- qk lo pass (w_hi·x_lo) ----
        for (int kk = 0; kk < 4; ++kk) {
            s16x8 ah[9];
#pragma unroll
            for (int tap = 0; tap < 9; ++tap)
                ah[tap] = *(const s16x8*)(wqh + (size_t)(tap * 64 + ocqk) * 256
                                          + ci0 + kk * 32 + (lane >> 4) * 8);
#pragma unroll
            for (int tap = 0; tap < 9; ++tap) {
                s16x8 bfr[4];
                READ_BFR(bfr, tap / 3, tap % 3, kk)
#pragma unroll
                for (int nf = 0; nf < 4; ++nf)
                    accq[nf] = __builtin_amdgcn_mfma_f32_16x16x32_bf16(ah[tap], bfr[nf], accq[nf], 0, 0, 0);
            }
        }
    }
    __syncthreads();   // btile dead; repurpose LDS for attention

    float (*qs)[33]   = (float(*)[33])smem;                //     0 ..  8448
    float (*ks)[33]   = (float(*)[33])(smem + 8448);       //  8448 .. 16896
    float (*S)[65]    = (float(*)[65])(smem + 16896);      // 16896 .. 33536
    ushort (*vs)[132] = (ushort(*)[132])(smem + 33536);    // 33536 .. 50432

    // q,k accumulators -> qs/ks (no global round-trip)
    {
        float (*dst)[33] = (w < 2) ? qs : ks;
        const int c0 = (w & 1) * 16 + (lane >> 4) * 4;
#pragma unroll
        for (int nf = 0; nf < 4; ++nf) {
            const int yy = nf * 16 + (lane & 15);
#pragma unroll
            for (int r = 0; r < 4; ++r) dst[yy][c0 + r] = accq[nf][r];
        }
    }
    // v accumulators -> vs (bf16)
#pragma unroll
    for (int m = 0; m < 2; ++m)
#pragma unroll
        for (int nf = 0; nf < 4; ++nf) {
            const int yy = nf * 16 + (lane & 15);
            const int c0 = w * 32 + m * 16 + (lane >> 4) * 4;
            ushort4 u;
            u.x = f2bf(accv[m][nf][0]); u.y = f2bf(accv[m][nf][1]);
            u.z = f2bf(accv[m][nf][2]); u.w = f2bf(accv[m][nf][3]);
            *(ushort4*)&vs[yy][c0] = u;
        }
    __syncthreads();

    // S = q k^T
    for (int idx = tid; idx < 4096; idx += 256) {
        const int i = idx >> 6, j = idx & 63;
        float s = 0.f;
#pragma unroll
        for (int c = 0; c < 32; ++c) s += qs[i][c] * ks[j][c];
        S[i][j] = s;
    }
    __syncthreads();

    // softmax rows: 4 lanes/row
    {
        const int row = tid >> 2, sub = tid & 3;
        float m = -INFINITY;
#pragma unroll
        for (int jj = 0; jj < 16; ++jj) m = fmaxf(m, S[row][sub * 16 + jj]);
        m = fmaxf(m, __shfl_xor(m, 1));
        m = fmaxf(m, __shfl_xor(m, 2));
        float e[16], sum = 0.f;
#pragma unroll
        for (int jj = 0; jj < 16; ++jj) {
            e[jj] = expf(S[row][sub * 16 + jj] - m);
            sum += e[jj];
        }
        sum += __shfl_xor(sum, 1);
        sum += __shfl_xor(sum, 2);
        const float inv = 1.f / sum;
#pragma unroll
        for (int jj = 0; jj < 16; ++jj) S[row][sub * 16 + jj] = e[jj] * inv;
    }
    __syncthreads();

    // attn write (coalesced)
    float* ao = attn_out + (size_t)bid * 4096;
    for (int idx = tid; idx < 4096; idx += 256)
        ao[idx] = S[idx >> 6][idx & 63];

    // AV
    {
        const int i = tid & 63, quad = tid >> 6;
        float fa[32];
#pragma unroll
        for (int cc = 0; cc < 32; ++cc) fa[cc] = 0.f;
        for (int j = 0; j < 64; ++j) {
            const float s = S[i][j];
#pragma unroll
            for (int cc = 0; cc < 32; ++cc)
                fa[cc] += s * bf2f(vs[j][quad * 32 + cc]);
        }
        ushort* avb = av + (size_t)bid * 8192 + (size_t)i * 128 + quad * 32;
#pragma unroll
        for (int cc = 0; cc < 32; ++cc) avb[cc] = f2bf(fa[cc]);
    }
}

// ---------------------------------------------------------------------------
// out_conv_mfma: block=(b,y,mt): M=128 oc, N=64 t, K=128ci*9tap.
// Weight frags batched per kk. out fp32 + residual.
// ---------------------------------------------------------------------------
__global__ __launch_bounds__(256, 2) void out_conv_mfma(
    const float* __restrict__ x,
    const ushort* __restrict__ av,
    const ushort* __restrict__ woT,
    const float* __restrict__ sigma,
    float* __restrict__ out)
{
    // XCD-bijective swizzle (2048 blocks, 256/XCD)
    const int bid  = ((blockIdx.x & 7) << 8) | (blockIdx.x >> 3);
    const int mt   = bid & 1;
    const int y    = (bid >> 1) & 63;
    const int b    = bid >> 7;
    const int tid  = threadIdx.x;
    const int lane = tid & 63;
    const int w    = tid >> 6;

    __shared__ ushort btile[3 * 66 * 128];

    f32x4 acc[2][4];
#pragma unroll
    for (int m = 0; m < 2; ++m)
#pragma unroll
        for (int nf = 0; nf < 4; ++nf) acc[m][nf] = (f32x4){0.f, 0.f, 0.f, 0.f};

    for (int idx = tid; idx < 198 * 16; idx += 256) {
        const int row = idx >> 4, ch = idx & 15;
        const int dy = row / 66, tl = row % 66;
        const int yp = y + dy - 1, tp = tl - 1;
        int4 val = {0, 0, 0, 0};
        if ((unsigned)yp < 64u && (unsigned)tp < 64u)
            val = *(const int4*)(av + ((((size_t)b * 64 + tp) * 64 + yp) * 128 + ch * 8));
        const int byte_off = row * 256 + ((ch * 16) ^ ((row & 7) << 4));
        *(int4*)((char*)btile + byte_off) = val;
    }
    __syncthreads();

    const int oc = mt * 128 + w * 32 + (lane & 15);
    for (int kk = 0; kk < 4; ++kk) {
        s16x8 wo_[9][2];
#pragma unroll
        for (int tap = 0; tap < 9; ++tap)
#pragma unroll
            for (int m = 0; m < 2; ++m)
                wo_[tap][m] = *(const s16x8*)(woT + (size_t)(tap * 256 + oc + m * 16) * 128
                                              + kk * 32 + (lane >> 4) * 8);
#pragma unroll
        for (int tap = 0; tap < 9; ++tap) {
            const int dy = tap / 3, dxp = tap % 3;
            s16x8 bfr[4];
#pragma unroll
            for (int nf = 0; nf < 4; ++nf) {
                const int tl = nf * 16 + (lane & 15) + dxp;
                const int row = dy * 66 + tl;
                const int bir = kk * 64 + (lane >> 4) * 16;
                bfr[nf] = *(const s16x8*)((const char*)btile + row * 256 + (bir ^ ((row & 7) << 4)));
            }
#pragma unroll
            for (int m = 0; m < 2; ++m)
#pragma unroll
                for (int nf = 0; nf < 4; ++nf)
                    acc[m][nf] = __builtin_amdgcn_mfma_f32_16x16x32_bf16(wo_[tap][m], bfr[nf], acc[m][nf], 0, 0, 0);
        }
    }

    const float s = sigma[0];
#pragma unroll
    for (int m = 0; m < 2; ++m)
#pragma unroll
        for (int nf = 0; nf < 4; ++nf)
#pragma unroll
            for (int r = 0; r < 4; ++r) {
                const int occ = mt * 128 + w * 32 + m * 16 + (lane >> 4) * 4 + r;
                const int t   = nf * 16 + (lane & 15);
                const size_t a = (((size_t)b * 256 + occ) * 64 + y) * 64 + t;
                out[a] = x[a] + s * acc[m][nf][r];
            }
}

// ---------------------------------------------------------------------------
extern "C" void kernel_launch(void* const* d_in, const int* in_sizes, int n_in,
                              void* d_out, int out_size, void* d_ws, size_t ws_size,
                              hipStream_t stream)
{
    const float* x     = (const float*)d_in[0];
    const float* wq    = (const float*)d_in[1];
    const float* wk    = (const float*)d_in[2];
    const float* wv    = (const float*)d_in[3];
    const float* wo    = (const float*)d_in[4];
    const float* sigma = (const float*)d_in[5];

    float* out      = (float*)d_out;                 // [16,256,64,64]
    float* attn_out = out + (size_t)16777216;        // [1024,64,64]

    // x hi/lo bf16 alias the out-image region (dead until out_conv_mfma):
    ushort* xh = (ushort*)d_out;                     // 16,777,216 bf16 = 32 MiB
    ushort* xl = xh + (size_t)16777216;              // 32 MiB (ends at attn_out)

    // d_ws: av | weights  (~17.8 MiB)
    ushort* av  = (ushort*)d_ws;                     // 8,388,608 bf16
    ushort* wvT = av + 8388608;                      // 294,912
    ushort* woT = wvT + 294912;                      // 294,912
    ushort* wqh = woT + 294912;                      // 147,456
    ushort* wql = wqh + 147456;                      // 147,456

    repack_w<<<2880, 256, 0, stream>>>(wq, wk, wv, wo, wvT, woT, wqh, wql);
    repack_x2<<<B_ * VDIM, 256, 0, stream>>>(x, xh, xl);
    qkvattn<<<B_ * TDIM, 256, 0, stream>>>(xh, xl, wvT, wqh, wql, attn_out, av);
    out_conv_mfma<<<B_ * VDIM * 2, 256, 0, stream>>>(x, av, woT, sigma, out);
}